// Round 5
// baseline (102.879 us; speedup 1.0000x reference)
//
#include <hip/hip_runtime.h>
#include <hip/hip_bf16.h>
#include <math.h>

#define B_   16
#define N_   32
#define I_   1152
#define DIN  16
#define D_   64
#define TI   8             // i's per k_xhat block
#define IB   (I_/TI)       // 144 i-tiles
#define IC   16            // i-chunks in routing (72 i each)
#define BND  (B_*N_*D_)    // 32768

#if __has_builtin(__builtin_amdgcn_exp2f)
#define EXP2(x) __builtin_amdgcn_exp2f(x)
#else
#define EXP2(x) exp2f(x)
#endif

#define LOG2E 1.4426950408889634f

typedef __attribute__((ext_vector_type(8))) short short8v;
typedef __attribute__((ext_vector_type(4))) float f32x4;

__device__ __forceinline__ float squash1(float s) {
    float sq = s * s;
    return (sq / (1.0f + sq)) * s * rsqrtf(sq + 1e-9f);
}
__device__ __forceinline__ unsigned short bfh(float v) {
    return __builtin_bit_cast(unsigned short, __float2bfloat16(v));
}
__device__ __forceinline__ float bff(unsigned short u) {
    unsigned int x = ((unsigned int)u) << 16;
    return __builtin_bit_cast(float, x);
}

// K1: x_hat via MFMA. Per (n,i): C[64d x 16b] = W[64d x 16k] * inp[16k x 16b].
// One mfma_f32_16x16x32_bf16 per (wave m-tile, i). K-slots 0..15 carry
// W_hi(bf16), slots 16..31 carry W_lo (bf16 residual), inputs duplicated:
// D = (W_hi + W_lo) . x  ==> fp32-grade W precision for free (K was padding).
// A-frag: lane row=l&15 (d within m-tile), k-octet=(l>>4); B-frag: col=l&15=b.
// C-frag: col=lane&15=b, row(d)=(lane>>4)*4+reg  [guide-verified layout].
// Output layout xh2[n][i][d][b] (bf16) matches C fragment for coalesced stores.
// Also accumulates s0 partials (sum over this block's 8 i's) -> part[ib][b][n][d].
__global__ __launch_bounds__(256) void k_xhat(const float* __restrict__ inp,
                                              const float* __restrict__ W,
                                              unsigned short* __restrict__ xh2,
                                              float* __restrict__ part) {
    const int bx = blockIdx.x;
    const int n  = bx / IB;
    const int ib = bx % IB;
    const int i0 = ib * TI;
    const int t  = threadIdx.x;
    const int l  = t & 63;
    const int mt = t >> 6;                 // wave id = d m-tile (0..3)
    const int row   = l & 15;              // A: d-in-tile  | B: b
    const int koctA = (l >> 4) & 1;        // k-octet within K=16 (lanes 32+ mirror)
    const bool loHalf = (l >= 32);         // these lanes supply W_lo

    const float* wbase = W + ((size_t)(n * I_ + i0) * 64 + mt * 16 + row) * 16 + koctA * 8;
    const float* ibase = inp + (size_t)row * (I_ * DIN) + (size_t)i0 * 16 + koctA * 8;

    f32x4 acc[TI];
    #pragma unroll
    for (int i = 0; i < TI; ++i) acc[i] = (f32x4){0.f, 0.f, 0.f, 0.f};

    #pragma unroll
    for (int i = 0; i < TI; ++i) {
        const float4* wp = (const float4*)(wbase + (size_t)i * 1024);
        const float4* xp = (const float4*)(ibase + (size_t)i * 16);
        float4 w0 = wp[0], w1 = wp[1];
        float4 x0 = xp[0], x1 = xp[1];
        float wv[8] = {w0.x, w0.y, w0.z, w0.w, w1.x, w1.y, w1.z, w1.w};
        float xv[8] = {x0.x, x0.y, x0.z, x0.w, x1.x, x1.y, x1.z, x1.w};
        short8v af, bf;
        #pragma unroll
        for (int j = 0; j < 8; ++j) {
            unsigned short hi = bfh(wv[j]);
            unsigned short lo = bfh(wv[j] - bff(hi));   // exact residual, then RNE
            af[j] = (short)(loHalf ? lo : hi);
            bf[j] = (short)bfh(xv[j]);
        }
        acc[i] = __builtin_amdgcn_mfma_f32_16x16x32_bf16(af, bf, acc[i], 0, 0, 0);
    }

    // store x_hat bf16, layout [n][i][d][b]
    #pragma unroll
    for (int i = 0; i < TI; ++i) {
        size_t rb = ((size_t)(n * I_ + i0 + i) * 64 + mt * 16 + (l >> 4) * 4) * 16 + (l & 15);
        #pragma unroll
        for (int r = 0; r < 4; ++r) xh2[rb + (size_t)r * 16] = bfh(acc[i][r]);
    }

    // s0 partial: sum over this block's 8 i's -> part[ib][b][n][d] (fp32)
    f32x4 s0v = acc[0];
    #pragma unroll
    for (int i = 1; i < TI; ++i) s0v += acc[i];
    size_t pidx = (((size_t)ib * B_ + (l & 15)) * N_ + n) * 64 + mt * 16 + (l >> 4) * 4;
    *(f32x4*)(part + pidx) = s0v;
}

// K2: coef = squash(mean over i of x_hat) — routing iteration 0.
__global__ __launch_bounds__(256) void k_out0(const float* __restrict__ part,
                                              float* __restrict__ coef) {
    const int t = blockIdx.x * 256 + threadIdx.x;   // (b,n,d) packed = coef index
    float s = 0.0f;
    for (int j = 0; j < IB; ++j) s += part[(size_t)j * BND + t];
    s *= (1.0f / (float)I_);
    coef[t] = squash1(s);
}

// K3: routing partial pass over xh2[n][i][d][b]. No max-tracking needed:
// |x|<~25, |coef|<=2 => |logit|<=50, exp safe in fp32. Accumulate z=sum(e),
// a=sum(e*x) per (d,b) over 72 i's. part2[ic][n][d][b][2] = {z,a}.
// grid = N_*IC blocks, 256 threads; thread t: d=t>>2, b=(t&3)*4+j (4 b's).
__global__ __launch_bounds__(256) void k_rpart(const unsigned short* __restrict__ xh2,
                                               const float* __restrict__ coef,
                                               float* __restrict__ part2) {
    const int bx = blockIdx.x;
    const int n  = bx >> 4;
    const int ic = bx & 15;
    const int t  = threadIdx.x;
    const int d  = t >> 2;
    const int bq = t & 3;

    const unsigned short* base = xh2 + ((size_t)n * I_ + (size_t)ic * (I_ / IC)) * 1024
                               + (size_t)d * 16 + bq * 4;
    float c2[4], z[4] = {0, 0, 0, 0}, a[4] = {0, 0, 0, 0};
    #pragma unroll
    for (int j = 0; j < 4; ++j) c2[j] = coef[((bq * 4 + j) * N_ + n) * D_ + d] * LOG2E;

    #pragma unroll 4
    for (int i = 0; i < I_ / IC; ++i) {
        const unsigned int* p = (const unsigned int*)(base + (size_t)i * 1024);
        unsigned int u0 = p[0], u1 = p[1];
        unsigned short s4[4] = {(unsigned short)(u0 & 0xffffu), (unsigned short)(u0 >> 16),
                                (unsigned short)(u1 & 0xffffu), (unsigned short)(u1 >> 16)};
        #pragma unroll
        for (int j = 0; j < 4; ++j) {
            float x = bff(s4[j]);
            float e = EXP2(x * c2[j]);
            z[j] += e;
            a[j] = fmaf(e, x, a[j]);
        }
    }

    // part2[ic][n][d][b][2], thread owns b = bq*4..bq*4+3 -> 8 contiguous floats
    size_t pidx = ((((size_t)ic * N_ + n) * 64 + d) * 16 + bq * 4) * 2;
    f32x4 v0 = {z[0], a[0], z[1], a[1]};
    f32x4 v1 = {z[2], a[2], z[3], a[3]};
    *(f32x4*)(part2 + pidx)     = v0;
    *(f32x4*)(part2 + pidx + 4) = v1;
}

// K4: routing finisher. gid packs (n,d,b) = part2's inner index order.
// final=0: coef += squash(a/z). final=1: out[b][n][d] = squash(a/z).
__global__ __launch_bounds__(256) void k_rfin(const float* __restrict__ part2,
                                              const float* __restrict__ coefIn,
                                              float* __restrict__ outp,
                                              int final_) {
    const int gid = blockIdx.x * 256 + threadIdx.x;     // ((n*64+d)*16)+b
    float Z = 0.0f, A = 0.0f;
    #pragma unroll
    for (int ic = 0; ic < IC; ++ic) {
        const float* p = part2 + ((size_t)ic * BND + gid) * 2;
        Z += p[0];
        A += p[1];
    }
    const int b = gid & 15, d = (gid >> 4) & 63, n = gid >> 10;
    const int ci = (b * N_ + n) * D_ + d;
    float o = squash1(A / Z);
    outp[ci] = final_ ? o : (coefIn[ci] + o);
}

extern "C" void kernel_launch(void* const* d_in, const int* in_sizes, int n_in,
                              void* d_out, int out_size, void* d_ws, size_t ws_size,
                              hipStream_t stream) {
    const float* inp = (const float*)d_in[0];
    const float* W   = (const float*)d_in[1];
    float* out = (float*)d_out;

    unsigned short* xh2 = (unsigned short*)d_ws;                    // 75,497,472 B
    float* part  = (float*)((char*)d_ws + 75497472);                // 18,874,368 B
    float* part2 = (float*)((char*)d_ws + 94371840);                //  4,194,304 B
    float* coef  = (float*)((char*)d_ws + 98566144);                //    131,072 B

    k_xhat<<<dim3(N_ * IB), dim3(256), 0, stream>>>(inp, W, xh2, part);
    k_out0<<<dim3(BND / 256), dim3(256), 0, stream>>>(part, coef);
    k_rpart<<<dim3(N_ * IC), dim3(256), 0, stream>>>(xh2, coef, part2);
    k_rfin <<<dim3(BND / 256), dim3(256), 0, stream>>>(part2, coef, coef, 0);
    k_rpart<<<dim3(N_ * IC), dim3(256), 0, stream>>>(xh2, coef, part2);
    k_rfin <<<dim3(BND / 256), dim3(256), 0, stream>>>(part2, coef, out, 1);
}